// Round 2
// baseline (17008.505 us; speedup 1.0000x reference)
//
#include <hip/hip_runtime.h>
#include <hip/hip_fp16.h>

// LSTM T=1024 B=64 I=H=512.
// Phase 1: xall[t,b, g*512+j] = inputs @ W_xg + b_g   (fp32 SGEMM, f16 store)
// Phase 2: 1 WG per batch element; h/c in LDS/regs; W_h packed f16 2x2 tiles
//          (uint4) streamed from L2 each step; v_dot2_f32_f16 inner product.
// T is processed in adaptive chunks so the f16 xall scratch fits in ws.
// Gate order g: 0=i, 1=f, 2=o, 3=u.

#define TT 1024
#define BB 64
#define II 512
#define HH 512
#define NG 2048          // 4*H flattened gate columns
#define KP 256           // H/2 packed k-pairs

typedef _Float16 half2_t __attribute__((ext_vector_type(2)));

__device__ inline float dot2f16(unsigned w, unsigned h, float acc) {
#if __has_builtin(__builtin_amdgcn_fdot2)
  return __builtin_amdgcn_fdot2(__builtin_bit_cast(half2_t, w),
                                __builtin_bit_cast(half2_t, h), acc, false);
#else
  half2_t wv = __builtin_bit_cast(half2_t, w);
  half2_t hv = __builtin_bit_cast(half2_t, h);
  return acc + (float)wv.x * (float)hv.x + (float)wv.y * (float)hv.y;
#endif
}

__device__ inline float fast_rcp(float x) {
#if __has_builtin(__builtin_amdgcn_rcpf)
  return __builtin_amdgcn_rcpf(x);
#else
  return 1.0f / x;
#endif
}

__device__ inline float fast_sigmoid(float x) {
  float e = __expf(-x);
  return fast_rcp(1.0f + e);
}

__device__ inline float fast_tanh(float x) {
  float ax = fabsf(x);
  float e = __expf(-2.0f * ax);
  float r = (1.0f - e) * fast_rcp(1.0f + e);
  return copysignf(r, x);
}

// ---------------- prep kernels (tiny) ----------------

// Bcat[k][c] fp32, c = g*512+j  (512*2048)
__global__ void prep_bcat(const float* __restrict__ Wxi, const float* __restrict__ Wxf,
                          const float* __restrict__ Wxo, const float* __restrict__ Wxu,
                          float* __restrict__ Bcat) {
  int idx = blockIdx.x * 256 + threadIdx.x;      // 1,048,576 total
  int c = idx & (NG - 1), k = idx >> 11;
  int g = c >> 9, j = c & (HH - 1);
  const float* W = (g == 0) ? Wxi : (g == 1) ? Wxf : (g == 2) ? Wxo : Wxu;
  Bcat[idx] = W[k * HH + j];
}

// bias[c] fp32 (2048)
__global__ void prep_bias(const float* __restrict__ bi, const float* __restrict__ bf,
                          const float* __restrict__ bo, const float* __restrict__ bu,
                          float* __restrict__ bias) {
  int c = blockIdx.x * 256 + threadIdx.x;
  int g = c >> 9, j = c & (HH - 1);
  bias[c] = ((g == 0) ? bi : (g == 1) ? bf : (g == 2) ? bo : bu)[j];
}

// Wp4[q][t] : uint4 tile for k-rows 4q..4q+3, cols (2t, 2t+1), q=0..127, t=0..1023
//   .x = pack(W[4q][2t],   W[4q+1][2t])     .y = pack(W[4q][2t+1],  W[4q+1][2t+1])
//   .z = pack(W[4q+2][2t], W[4q+3][2t])     .w = pack(W[4q+2][2t+1],W[4q+3][2t+1])
__global__ void prep_wp4(const float* __restrict__ Whi, const float* __restrict__ Whf,
                         const float* __restrict__ Who, const float* __restrict__ Whu,
                         uint4* __restrict__ Wp4) {
  int idx = blockIdx.x * 256 + threadIdx.x;      // 131072 total
  int t = idx & 1023, q = idx >> 10;
  int c0 = 2 * t;
  int g = c0 >> 9, j0 = c0 & (HH - 1), j1 = j0 + 1;
  const float* W = (g == 0) ? Whi : (g == 1) ? Whf : (g == 2) ? Who : Whu;
  const float* r0 = W + (size_t)(4 * q) * HH;
  uint4 v;
  v.x = __builtin_bit_cast(unsigned, __floats2half2_rn(r0[j0],          r0[HH + j0]));
  v.y = __builtin_bit_cast(unsigned, __floats2half2_rn(r0[j1],          r0[HH + j1]));
  v.z = __builtin_bit_cast(unsigned, __floats2half2_rn(r0[2 * HH + j0], r0[3 * HH + j0]));
  v.w = __builtin_bit_cast(unsigned, __floats2half2_rn(r0[2 * HH + j1], r0[3 * HH + j1]));
  Wp4[idx] = v;
}

// ---------------- phase 1: fp32 SGEMM 128x128 tile, f16 store ----------------
// A[M,512] @ Bcat[512,2048] + bias -> xall f16   (M = TCH*BB per chunk)

__global__ __launch_bounds__(256, 4)
void sgemm_x(const float* __restrict__ A, const float* __restrict__ Bm,
             const float* __restrict__ bias, __half* __restrict__ Cx) {
  __shared__ float As[8][128];   // transposed: As[k][m]
  __shared__ float Bs[8][128];
  const int tid = threadIdx.x;
  const int r0 = blockIdx.y * 128;
  const int c0 = blockIdx.x * 128;
  const int tx = tid & 15, ty = tid >> 4;

  float acc[8][8];
#pragma unroll
  for (int i = 0; i < 8; ++i)
#pragma unroll
    for (int j = 0; j < 8; ++j) acc[i][j] = 0.f;

  const int arow = tid >> 1;           // 0..127
  const int akq  = (tid & 1) * 4;      // 0 / 4
  const int bk   = tid >> 5;           // 0..7
  const int bc   = (tid & 31) * 4;     // 0..124

  for (int k0 = 0; k0 < 512; k0 += 8) {
    float4 va = *(const float4*)(A + (size_t)(r0 + arow) * 512 + k0 + akq);
    float4 vb = *(const float4*)(Bm + (size_t)(k0 + bk) * NG + c0 + bc);
    As[akq + 0][arow] = va.x;
    As[akq + 1][arow] = va.y;
    As[akq + 2][arow] = va.z;
    As[akq + 3][arow] = va.w;
    *(float4*)&Bs[bk][bc] = vb;
    __syncthreads();
#pragma unroll
    for (int k = 0; k < 8; ++k) {
      float a[8], b[8];
      *(float4*)&a[0] = *(const float4*)&As[k][ty * 8];
      *(float4*)&a[4] = *(const float4*)&As[k][ty * 8 + 4];
      *(float4*)&b[0] = *(const float4*)&Bs[k][tx * 8];
      *(float4*)&b[4] = *(const float4*)&Bs[k][tx * 8 + 4];
#pragma unroll
      for (int i = 0; i < 8; ++i)
#pragma unroll
        for (int j = 0; j < 8; ++j) acc[i][j] = fmaf(a[i], b[j], acc[i][j]);
    }
    __syncthreads();
  }

  float bsv[8];
  *(float4*)&bsv[0] = *(const float4*)(bias + c0 + tx * 8);
  *(float4*)&bsv[4] = *(const float4*)(bias + c0 + tx * 8 + 4);
#pragma unroll
  for (int i = 0; i < 8; ++i) {
    union { __half h[8]; int4 v; } u;
#pragma unroll
    for (int j = 0; j < 8; ++j) u.h[j] = __float2half(acc[i][j] + bsv[j]);
    *reinterpret_cast<int4*>(Cx + (size_t)(r0 + ty * 8 + i) * NG + c0 + tx * 8) = u.v;
  }
}

// ---------------- phase 2: recurrent scan chunk, 1 WG / batch ----------------

__global__ __launch_bounds__(1024, 1)
void lstm_rec(const uint4* __restrict__ Wp4, const __half* __restrict__ xall,
              const float* __restrict__ hin, const float* __restrict__ cin,
              float* __restrict__ out, float* __restrict__ hout,
              float* __restrict__ cout, int nsteps) {
  __shared__ __align__(16) unsigned h2s[KP];   // packed f16 pairs of h
  __shared__ float gsm[NG];                    // gate pre-activations
  const int b = blockIdx.x;
  const int tid = threadIdx.x;

  if (tid < HH)
    ((unsigned short*)h2s)[tid] =
        __builtin_bit_cast(unsigned short, __float2half(hin[(size_t)b * HH + tid]));
  float c_reg = (tid < HH) ? cin[(size_t)b * HH + tid] : 0.f;
  float h_reg = 0.f;
  __syncthreads();

  const uint4* wbase = Wp4 + tid;   // cols (2*tid, 2*tid+1); q-stride 1024 uint4

  for (int t = 0; t < nsteps; ++t) {
    const __half2 xv = *(const __half2*)(xall + ((size_t)t * BB + b) * NG + 2 * tid);
    float2 xf = __half22float2(xv);
    float acc0 = xf.x, acc1 = xf.y, acc0b = 0.f, acc1b = 0.f;

#pragma unroll 4
    for (int q = 0; q < 128; q += 2) {
      uint4 hh = ((const uint4*)h2s)[q >> 1];        // lane-uniform -> broadcast
      uint4 w0 = wbase[(size_t)q * 1024];
      uint4 w1 = wbase[(size_t)(q + 1) * 1024];
      acc0  = dot2f16(w0.x, hh.x, acc0);  acc1  = dot2f16(w0.y, hh.x, acc1);
      acc0b = dot2f16(w0.z, hh.y, acc0b); acc1b = dot2f16(w0.w, hh.y, acc1b);
      acc0  = dot2f16(w1.x, hh.z, acc0);  acc1  = dot2f16(w1.y, hh.z, acc1);
      acc0b = dot2f16(w1.z, hh.w, acc0b); acc1b = dot2f16(w1.w, hh.w, acc1b);
    }

    gsm[2 * tid]     = acc0 + acc0b;
    gsm[2 * tid + 1] = acc1 + acc1b;
    __syncthreads();

    if (tid < HH) {
      float gi = gsm[tid];
      float gf = gsm[HH + tid];
      float go = gsm[2 * HH + tid];
      float gu = gsm[3 * HH + tid];
      float iv = fast_sigmoid(gi);
      float fv = fast_sigmoid(gf);
      float ov = fast_sigmoid(go);
      float uv = fast_tanh(gu);
      c_reg = fv * c_reg + iv * uv;
      h_reg = ov * fast_tanh(c_reg);
      out[((size_t)t * BB + b) * HH + tid] = h_reg;
      ((unsigned short*)h2s)[tid] =
          __builtin_bit_cast(unsigned short, __float2half(h_reg));
    }
    __syncthreads();
  }

  if (tid < HH) {
    hout[(size_t)b * HH + tid] = h_reg;
    cout[(size_t)b * HH + tid] = c_reg;
  }
}

// ---------------- launch ----------------

extern "C" void kernel_launch(void* const* d_in, const int* in_sizes, int n_in,
                              void* d_out, int out_size, void* d_ws, size_t ws_size,
                              hipStream_t stream) {
  const float* inputs = (const float*)d_in[0];
  const float* h0     = (const float*)d_in[1];
  const float* c0v    = (const float*)d_in[2];
  const float* Wxi    = (const float*)d_in[3];
  const float* Whi    = (const float*)d_in[4];
  const float* Wxf    = (const float*)d_in[5];
  const float* Whf    = (const float*)d_in[6];
  const float* Wxu    = (const float*)d_in[7];
  const float* Whu    = (const float*)d_in[8];
  const float* Wxo    = (const float*)d_in[9];
  const float* Who    = (const float*)d_in[10];
  const float* bi     = (const float*)d_in[11];
  const float* bf     = (const float*)d_in[12];
  const float* bo     = (const float*)d_in[13];
  const float* bu     = (const float*)d_in[14];

  const size_t BCAT_BYTES = (size_t)512 * NG * 4;              // 4 MiB
  const size_t BIAS_BYTES = (size_t)NG * 4;                    // 8 KiB
  const size_t WP4_BYTES  = (size_t)128 * 1024 * 16;           // 2 MiB
  const size_t ST_BYTES   = (size_t)BB * HH * 4;               // 128 KiB each
  const size_t FIXED      = BCAT_BYTES + BIAS_BYTES + WP4_BYTES + 2 * ST_BYTES;

  // Pick largest chunk length (in timesteps) whose xall buffer fits in ws.
  int TCH = TT;
  while (TCH > 8 && FIXED + (size_t)TCH * BB * NG * 2 > ws_size) TCH >>= 1;

  char* ws = (char*)d_ws;
  float*  Bcat    = (float*)ws;
  float*  bias    = (float*)(ws + BCAT_BYTES);
  uint4*  Wp4     = (uint4*)(ws + BCAT_BYTES + BIAS_BYTES);
  float*  h_state = (float*)(ws + BCAT_BYTES + BIAS_BYTES + WP4_BYTES);
  float*  c_state = (float*)(ws + BCAT_BYTES + BIAS_BYTES + WP4_BYTES + ST_BYTES);
  __half* xall    = (__half*)(ws + FIXED);

  float* out = (float*)d_out;
  float* hT  = out + (size_t)TT * BB * HH;
  float* cT  = hT + (size_t)BB * HH;

  prep_bcat<<<(512 * NG) / 256, 256, 0, stream>>>(Wxi, Wxf, Wxo, Wxu, Bcat);
  prep_bias<<<NG / 256, 256, 0, stream>>>(bi, bf, bo, bu, bias);
  prep_wp4<<<(128 * 1024) / 256, 256, 0, stream>>>(Whi, Whf, Who, Whu, Wp4);

  const int nch = TT / TCH;
  for (int ch = 0; ch < nch; ++ch) {
    const int t0 = ch * TCH;
    sgemm_x<<<dim3(NG / 128, (TCH * BB) / 128), 256, 0, stream>>>(
        inputs + (size_t)t0 * BB * II, Bcat, bias, xall);
    const float* hin = (ch == 0) ? h0 : h_state;
    const float* cin = (ch == 0) ? c0v : c_state;
    float* hout = (ch == nch - 1) ? hT : h_state;
    float* cout = (ch == nch - 1) ? cT : c_state;
    lstm_rec<<<BB, 1024, 0, stream>>>(Wp4, xall, hin, cin,
                                      out + (size_t)t0 * BB * HH, hout, cout, TCH);
  }
}